// Round 12
// baseline (117.361 us; speedup 1.0000x reference)
//
#include <hip/hip_runtime.h>
#include <hip/hip_bf16.h>
#include <math.h>

#define BB   4
#define CCH  256
#define KK   8
#define NPIX 16384
#define TILE 64
#define NBLK 256           // blocks per batch = NPIX/TILE
#define TEMP_INV 1.25f     // 1/0.8
#define EPSF 1e-6f

__device__ __forceinline__ float bf_lo(unsigned int u) { return __uint_as_float(u << 16); }
__device__ __forceinline__ float bf_hi(unsigned int u) { return __uint_as_float(u & 0xffff0000u); }
__device__ __forceinline__ unsigned short bfbits(float f) {
    __hip_bfloat16 h = __float2bfloat16(f);
    return *reinterpret_cast<unsigned short*>(&h);
}
__device__ __forceinline__ unsigned int pack_bf2(float a, float b) {
    return (unsigned int)bfbits(a) | ((unsigned int)bfbits(b) << 16);
}

// ---------------------------------------------------------------------------
// Pass kernel, within-wave phase-1 redesign (r12):
//  - wave g owns pixels 8g..8g+7; lane (px = 8g+(l&7), cgrp = l>>3) covers 32
//    channels; cr[8] completed in-wave via shfl_xor butterfly (8/16/32) ->
//    per-lane softmax, NO cross-wave staging, no big cross_s buffer.
//  - proto (or seeds) staged once into 4KB bf16 LDS [cc][cgrp][k]: b128
//    broadcast reads, conflict-free (8 x 16B spans = all 32 banks).
//  - LDS 38.2KB -> 4 blocks/CU; grid 1024 = one scheduling round (the 3/CU
//    768-slot config ran passes in 2 uneven rounds = the 13.5us vs 10 floor).
//  - phase 2 writes part_num directly (no acc staging, one fewer barrier).
// [r4/r10 lesson: feats is L3-resident -- no bf16 global cache. r7/r9 lesson:
//  no cross-block sync. r5 lesson: no serial 256-deep load chains.]
// MODE 0: seeds + bias, computes f_sq. MODE 1: iteration, f_sq dropped
// (softmax-invariant). MODE 2: iteration + emit logits/probs.
// fb tile swizzle: word wp = (px>>1) ^ (((c&15)^(c>>5))<<1)  (cgrp term keeps
// the 8-rows-per-store-instr pattern spread across banks).
// ---------------------------------------------------------------------------
template<int MODE>
__global__ __launch_bounds__(512, 8)
void skm_pass(const float* __restrict__ feats,
              const float* __restrict__ seed_w,
              const float* __restrict__ seed_b,
              const float* __restrict__ proto_t,   // [b][256][8]
              const float* __restrict__ psq_part,  // [b][8][8]
              float* __restrict__ fsq,
              float* __restrict__ part_num,
              float* __restrict__ part_den,
              float* __restrict__ logits_out,
              float* __restrict__ probs_out)
{
    __shared__ unsigned int fb_s[CCH][32];      // 32 KB: bf16 feats tile, swizzled
    __shared__ unsigned int proto_s[32][8][4];  // 4 KB: bf16 proto [cc][cgrp][k-pair]
    __shared__ float w_s[KK][68];               // 2.18 KB (272B rows, 16B-aligned)
    __shared__ float psq_s[8];                  // -TI*p_sq (M1/2) or seed_b (M0)

    const int t   = threadIdx.x;
    const int bid = blockIdx.x;
    const int b   = bid >> 8;
    const int blk = bid & 255;
    const int n0  = blk * TILE;

    // ---- staging: proto -> bf16 LDS, psq/seed_b -> psq_s ----
    {
        const int c = t >> 1, kh = t & 1;       // kh: k 0-3 / 4-7
        if (MODE == 0) {
            const float s0 = seed_w[(4 * kh + 0) * CCH + c];
            const float s1 = seed_w[(4 * kh + 1) * CCH + c];
            const float s2 = seed_w[(4 * kh + 2) * CCH + c];
            const float s3 = seed_w[(4 * kh + 3) * CCH + c];
            proto_s[c & 31][c >> 5][2 * kh]     = pack_bf2(s0, s1);
            proto_s[c & 31][c >> 5][2 * kh + 1] = pack_bf2(s2, s3);
            if (t < 8) psq_s[t] = seed_b[t];
        } else {
            const float4 pv = ((const float4*)(proto_t + (size_t)b * CCH * KK))[t];
            proto_s[c & 31][c >> 5][2 * kh]     = pack_bf2(pv.x, pv.y);
            proto_s[c & 31][c >> 5][2 * kh + 1] = pack_bf2(pv.z, pv.w);
            if (t < 8) {
                const float4 q0 = ((const float4*)psq_part)[(b * KK + t) * 2];
                const float4 q1 = ((const float4*)psq_part)[(b * KK + t) * 2 + 1];
                psq_s[t] = -TEMP_INV * (((q0.x + q0.y) + (q0.z + q0.w))
                                      + ((q1.x + q1.y) + (q1.z + q1.w)));
            }
        }
    }
    __syncthreads();

    // ---- phase 1: per-lane 32-channel partial dot, in-wave butterfly ----
    const int lane = t & 63;
    const int g    = t >> 6;                    // wave -> pixel group
    const int px   = (g << 3) + (lane & 7);     // 0..63
    const int cgrp = lane >> 3;                 // 0..7 (32 channels each)
    const int c0   = cgrp << 5;
    const float* fcol = feats + ((size_t)b * CCH + c0) * NPIX + n0 + px;

    float cr[KK];
    #pragma unroll
    for (int k = 0; k < KK; ++k) cr[k] = 0.f;
    float fs = 0.f;

    #pragma unroll 8
    for (int cc = 0; cc < 32; ++cc) {
        const float f = fcol[(size_t)cc * NPIX];            // 8x32B sectors/wave
        if (MODE == 0) fs = fmaf(f, f, fs);
        const int c  = c0 + cc;
        const int wp = (px >> 1) ^ ((((c & 15) ^ (c >> 5))) << 1);
        ((unsigned short*)fb_s)[(c << 6) + (wp << 1) + (px & 1)] = bfbits(f);
        const uint4 pv = *(const uint4*)&proto_s[cc][cgrp][0];  // b128 bcast, conflict-free
        cr[0] = fmaf(bf_lo(pv.x), f, cr[0]);
        cr[1] = fmaf(bf_hi(pv.x), f, cr[1]);
        cr[2] = fmaf(bf_lo(pv.y), f, cr[2]);
        cr[3] = fmaf(bf_hi(pv.y), f, cr[3]);
        cr[4] = fmaf(bf_lo(pv.z), f, cr[4]);
        cr[5] = fmaf(bf_hi(pv.z), f, cr[5]);
        cr[6] = fmaf(bf_lo(pv.w), f, cr[6]);
        cr[7] = fmaf(bf_hi(pv.w), f, cr[7]);
    }
    #pragma unroll
    for (int k = 0; k < KK; ++k) {              // complete 256-ch dot in-wave
        cr[k] += __shfl_xor(cr[k], 8, 64);
        cr[k] += __shfl_xor(cr[k], 16, 64);
        cr[k] += __shfl_xor(cr[k], 32, 64);
    }
    if (MODE == 0) {
        fs += __shfl_xor(fs, 8, 64);
        fs += __shfl_xor(fs, 16, 64);
        fs += __shfl_xor(fs, 32, 64);
        if (cgrp == 0) fsq[b * NPIX + n0 + px] = fs;
    }

    // ---- per-lane softmax over k (all 8 in registers) ----
    {
        float fvt = 0.f;
        if (MODE == 2) fvt = -TEMP_INV * fsq[b * NPIX + n0 + px];
        float lg[KK];
        #pragma unroll
        for (int k = 0; k < KK; ++k) {
            if (MODE == 0)      lg[k] = cr[k] + psq_s[k];
            else if (MODE == 1) lg[k] = fmaf(2.f * TEMP_INV, cr[k], psq_s[k]);
            else                lg[k] = fmaf(2.f * TEMP_INV, cr[k], psq_s[k] + fvt);
        }
        float m = lg[0];
        #pragma unroll
        for (int k = 1; k < KK; ++k) m = fmaxf(m, lg[k]);
        float e[KK], ssum = 0.f;
        #pragma unroll
        for (int k = 0; k < KK; ++k) { e[k] = expf(lg[k] - m); ssum += e[k]; }
        const float inv = 1.f / ssum;
        // lane (cgrp==k) publishes cluster k for its pixel; static-index select
        float wv = e[0], lgo = lg[0];
        #pragma unroll
        for (int k = 1; k < KK; ++k)
            if (cgrp == k) { wv = e[k]; lgo = lg[k]; }
        wv *= inv;
        w_s[cgrp][px] = wv;
        if (MODE == 2) {
            logits_out[((size_t)b * KK + cgrp) * NPIX + n0 + px] = lgo;
            probs_out [((size_t)b * KK + cgrp) * NPIX + n0 + px] = wv;
        }
    }
    __syncthreads();

    // ---- per-block denominator partials (threads 0..255) ----
    if (t < 256) {
        const int kk = t >> 5, ll = t & 31;
        float s = w_s[kk][2 * ll] + w_s[kk][2 * ll + 1];
        s += __shfl_xor(s, 16, 64);
        s += __shfl_xor(s, 8, 64);
        s += __shfl_xor(s, 4, 64);
        s += __shfl_xor(s, 2, 64);
        s += __shfl_xor(s, 1, 64);
        if (ll == 0) part_den[(b * NBLK + blk) * KK + kk] = s;
    }

    // ---- phase 2: num[k][c] from bf16 LDS tile, direct part_num write ----
    {
        const int c  = t & 255, kh = t >> 8;    // kh: k 0-3 / 4-7
        const int sw = (c & 15) ^ (c >> 5);     // uint2-index swizzle
        const uint2* row2 = (const uint2*)fb_s[c];
        const int kb = kh * 4;
        float acc[4];
        #pragma unroll
        for (int kk2 = 0; kk2 < 4; ++kk2) acc[kk2] = 0.f;
        #pragma unroll
        for (int j = 0; j < 16; ++j) {
            const uint2 u = row2[j ^ sw];
            const float f0 = bf_lo(u.x), f1 = bf_hi(u.x);
            const float f2 = bf_lo(u.y), f3 = bf_hi(u.y);
            const int pxj = 4 * j;
            #pragma unroll
            for (int kk2 = 0; kk2 < 4; ++kk2) {
                const float4 w4 = *(const float4*)&w_s[kb + kk2][pxj];  // bcast b128
                acc[kk2] = fmaf(f3, w4.w, fmaf(f2, w4.z,
                           fmaf(f1, w4.y, fmaf(f0, w4.x, acc[kk2]))));
            }
        }
        #pragma unroll
        for (int kk2 = 0; kk2 < 4; ++kk2)
            part_num[(((size_t)b * NBLK + blk) * KK + (kb + kk2)) * CCH + c] = acc[kk2];
    }
}

// ---------------------------------------------------------------------------
// Reduce (r11-proven, 512 threads, 16-way j-split): 256 blocks = 32 (b,k) x 8
// channel-chunks; writes proto_t (+proto_out) AND psq_part chunk.
// FINAL=true: blocks >= 256 do the bilinear x4 upsample (512-wide).
// ---------------------------------------------------------------------------
template<bool FINAL>
__global__ __launch_bounds__(512)
void skm_reduce(const float* __restrict__ part_num,
                const float* __restrict__ part_den,
                float* __restrict__ proto_t,
                float* __restrict__ psq_part,
                float* __restrict__ proto_out,
                const float* __restrict__ probs_ws,
                float* __restrict__ probs_full)
{
    const int bid = blockIdx.x;
    if (FINAL && bid >= 256) {
        // ---- upsample role: half-pixel bilinear x4, edge clamp ----
        const int gid = (bid - 256) * 512 + threadIdx.x;   // 0..2097151
        const int jb = gid & 127;
        const int i  = (gid >> 7) & 511;
        const int bk = gid >> 16;
        const float* src = probs_ws + (size_t)bk * NPIX;
        const float y   = i * 0.25f - 0.375f;
        const float y0f = floorf(y);
        const float fy  = y - y0f;
        const int   y0  = (int)y0f;
        const int ya = min(max(y0, 0), 127);
        const int yb = min(max(y0 + 1, 0), 127);
        const int xm = max(jb - 1, 0);
        const int xp = min(jb + 1, 127);
        const float* r0 = src + ya * 128;
        const float* r1 = src + yb * 128;
        const float wy0 = 1.f - fy;
        const float am = r0[xm] * wy0 + r1[xm] * fy;
        const float ac = r0[jb] * wy0 + r1[jb] * fy;
        const float ap = r0[xp] * wy0 + r1[xp] * fy;
        float4 o;
        o.x = 0.375f * am + 0.625f * ac;
        o.y = 0.125f * am + 0.875f * ac;
        o.z = 0.875f * ac + 0.125f * ap;
        o.w = 0.625f * ac + 0.375f * ap;
        ((float4*)probs_full)[gid] = o;
        return;
    }

    const int cq = bid & 7;
    const int bk = bid >> 3;             // 0..31
    const int b = bk >> 3, k = bk & 7;
    const int t = threadIdx.x;

    __shared__ float red[16][32];
    __shared__ float den_s[4];

    // denominator: threads 0-255 read 256 block-partials, per-wave shuffle tree
    float dv = (t < 256) ? part_den[(b * NBLK + t) * KK + k] : 0.f;
    dv += __shfl_xor(dv, 32, 64);
    dv += __shfl_xor(dv, 16, 64);
    dv += __shfl_xor(dv, 8, 64);
    dv += __shfl_xor(dv, 4, 64);
    dv += __shfl_xor(dv, 2, 64);
    dv += __shfl_xor(dv, 1, 64);
    if (t < 256 && (t & 63) == 0) den_s[t >> 6] = dv;

    // numerator: 16-way j-split over this role's 32 channels
    const int jj = t >> 5, cl = t & 31;
    const int c = cq * 32 + cl;
    float s = 0.f;
    #pragma unroll 4
    for (int j = 0; j < 16; ++j)
        s += part_num[(((size_t)b * NBLK + jj * 16 + j) * KK + k) * CCH + c];
    red[jj][cl] = s;
    __syncthreads();

    if (t < 32) {
        const float den = den_s[0] + den_s[1] + den_s[2] + den_s[3] + EPSF;
        float pv = 0.f;
        #pragma unroll
        for (int j2 = 0; j2 < 16; ++j2) pv += red[j2][t];
        pv /= den;
        const int c2 = cq * 32 + t;
        proto_t[((size_t)b * CCH + c2) * KK + k] = pv;
        if (proto_out) proto_out[(b * KK + k) * CCH + c2] = pv;
        float q = pv * pv;                               // psq chunk partial
        q += __shfl_xor(q, 16, 64);
        q += __shfl_xor(q, 8, 64);
        q += __shfl_xor(q, 4, 64);
        q += __shfl_xor(q, 2, 64);
        q += __shfl_xor(q, 1, 64);
        if (t == 0) psq_part[(b * KK + k) * 8 + cq] = q;
    }
}

// ---------------------------------------------------------------------------
extern "C" void kernel_launch(void* const* d_in, const int* in_sizes, int n_in,
                              void* d_out, int out_size, void* d_ws, size_t ws_size,
                              hipStream_t stream)
{
    const float* feats  = (const float*)d_in[0];   // [4][256][16384]
    const float* seed_w = (const float*)d_in[1];   // [16][256] (first 8 rows)
    const float* seed_b = (const float*)d_in[2];   // [16]

    float* out        = (float*)d_out;
    float* probs_full = out;                        // 4*8*512*512 = 8388608
    float* proto_out  = out + 8388608;              // 4*8*256     = 8192
    float* logits_out = out + 8388608 + 8192;       // 4*8*128*128 = 524288

    float* ws       = (float*)d_ws;
    float* fsq      = ws;                           // 65536
    float* part_den = ws + 65536;                   // 4*256*8 = 8192
    float* proto_t  = part_den + 8192;              // 8192
    float* psq_part = proto_t + 8192;               // 256
    float* probs_ws = psq_part + 256;               // 524288
    float* part_num = probs_ws + 524288;            // 2097152 (~10.7 MB total)

    const dim3 pg(BB * NBLK), pb(512);
    const dim3 rg(256), rb(512);

    // seed pass + initial proto
    skm_pass<0><<<pg, pb, 0, stream>>>(feats, seed_w, seed_b, proto_t, psq_part,
                                       fsq, part_num, part_den, nullptr, nullptr);
    skm_reduce<false><<<rg, rb, 0, stream>>>(part_num, part_den, proto_t, psq_part,
                                             nullptr, probs_ws, probs_full);
    // cluster iterations 1,2
    skm_pass<1><<<pg, pb, 0, stream>>>(feats, seed_w, seed_b, proto_t, psq_part,
                                       fsq, part_num, part_den, nullptr, nullptr);
    skm_reduce<false><<<rg, rb, 0, stream>>>(part_num, part_den, proto_t, psq_part,
                                             nullptr, probs_ws, probs_full);
    skm_pass<1><<<pg, pb, 0, stream>>>(feats, seed_w, seed_b, proto_t, psq_part,
                                       fsq, part_num, part_den, nullptr, nullptr);
    skm_reduce<false><<<rg, rb, 0, stream>>>(part_num, part_den, proto_t, psq_part,
                                             nullptr, probs_ws, probs_full);
    // iteration 3: emit logits_map + probs(=assign)
    skm_pass<2><<<pg, pb, 0, stream>>>(feats, seed_w, seed_b, proto_t, psq_part,
                                       fsq, part_num, part_den, logits_out, probs_ws);
    // final reduce (proto -> d_out) + fused bilinear x4 upsample (512-wide)
    skm_reduce<true><<<dim3(256 + 4096), rb, 0, stream>>>(part_num, part_den, proto_t, psq_part,
                                                          proto_out, probs_ws, probs_full);
}